// Round 1
// baseline (513.582 us; speedup 1.0000x reference)
//
#include <hip/hip_runtime.h>
#include <cstdint>
#include <cstddef>
#include <math.h>

#define BOX_W_C  5.0f
#define GIOU_W_C 2.0f
#define OBJ_W_C  1.0f
#define CLS_W_C  1.5f
#define CTR_W_C  0.5f
#define POS_RADIUS_C 1.0f
#define MAXM 128

// focal element: a_t * ce * (1-p_t)^2 with alpha=0.25, gamma=2, t in {0,1}
__device__ __forceinline__ float focal_elem(float x, float t) {
    float ax = fabsf(x);
    float e  = __expf(-ax);
    float lg = __logf(1.0f + e);              // log1p(exp(-|x|)), e in (0,1]
    float ce = fmaxf(x, 0.0f) - x * t + lg;
    float p  = (x >= 0.0f) ? (1.0f / (1.0f + e)) : (e / (1.0f + e));  // sigmoid
    float p_t = p * t + (1.0f - p) * (1.0f - t);
    float a_t = 0.25f * t + 0.75f * (1.0f - t);
    float om  = 1.0f - p_t;
    return a_t * ce * om * om;
}

// Kernel 1: one block per (b,m). Computes per-GT: x1,y1,x2,y2,cx,cy,area,
// has_candidate (any inside_box & inside_center over L), and the fallback
// best location (first-occurrence argmin matching jnp.argmin semantics).
__global__ void gt_assign_kernel(const float* __restrict__ locations,
                                 const float* __restrict__ gt_boxes,
                                 const int* __restrict__ gh_p,
                                 const int* __restrict__ gw_p,
                                 int L, int M,
                                 float* __restrict__ info,
                                 int* __restrict__ flags,
                                 float* __restrict__ accums) {
    int bm  = blockIdx.x;
    int tid = threadIdx.x;
    if (bm == 0 && tid < 8) accums[tid] = 0.0f;   // zero accumulators (ws is 0xAA-poisoned)

    const float* gb = gt_boxes + (size_t)bm * 4;
    float cx = gb[0], cy = gb[1], w = gb[2], h = gb[3];
    float x1 = cx - w * 0.5f, y1 = cy - h * 0.5f;
    float x2 = cx + w * 0.5f, y2 = cy + h * 0.5f;
    float area = w * h;
    float rx = POS_RADIUS_C / (float)gw_p[0];
    float ry = POS_RADIUS_C / (float)gh_p[0];

    float bin_v  = INFINITY; int bin_i  = 0x7fffffff;  // argmin of dist masked to inside_box
    float ball_v = INFINITY; int ball_i = 0x7fffffff;  // argmin of dist (unmasked)
    int any_cand = 0, any_in = 0;

    for (int l = tid; l < L; l += blockDim.x) {
        float lx = locations[2 * l], ly = locations[2 * l + 1];
        bool inb = (lx > x1) && (ly > y1) && (lx < x2) && (ly < y2);
        bool inc = (fabsf(lx - cx) <= rx) && (fabsf(ly - cy) <= ry);
        any_cand |= (int)(inb && inc);
        any_in   |= (int)inb;
        float dx = lx - cx, dy = ly - cy;
        float dist = dx * dx + dy * dy;
        if (dist < ball_v) { ball_v = dist; ball_i = l; }   // strict < keeps first occurrence
        float din = inb ? dist : INFINITY;
        if (din < bin_v) { bin_v = din; bin_i = l; }
    }

    __shared__ float s_v1[256]; __shared__ int s_i1[256];
    __shared__ float s_v2[256]; __shared__ int s_i2[256];
    __shared__ int s_c[256]; __shared__ int s_n[256];
    s_v1[tid] = bin_v;  s_i1[tid] = bin_i;
    s_v2[tid] = ball_v; s_i2[tid] = ball_i;
    s_c[tid] = any_cand; s_n[tid] = any_in;
    __syncthreads();
    for (int s = blockDim.x / 2; s > 0; s >>= 1) {
        if (tid < s) {
            if (s_v1[tid + s] < s_v1[tid] ||
                (s_v1[tid + s] == s_v1[tid] && s_i1[tid + s] < s_i1[tid])) {
                s_v1[tid] = s_v1[tid + s]; s_i1[tid] = s_i1[tid + s];
            }
            if (s_v2[tid + s] < s_v2[tid] ||
                (s_v2[tid + s] == s_v2[tid] && s_i2[tid + s] < s_i2[tid])) {
                s_v2[tid] = s_v2[tid + s]; s_i2[tid] = s_i2[tid + s];
            }
            s_c[tid] |= s_c[tid + s];
            s_n[tid] |= s_n[tid + s];
        }
        __syncthreads();
    }
    if (tid == 0) {
        int best = s_n[0] ? s_i1[0] : s_i2[0];
        flags[bm * 2]     = s_c[0];
        flags[bm * 2 + 1] = best;
        float* oi = info + (size_t)bm * 8;
        oi[0] = x1; oi[1] = y1; oi[2] = x2; oi[3] = y2;
        oi[4] = cx; oi[5] = cy; oi[6] = area; oi[7] = 0.0f;
    }
}

// Kernel 2: one thread per (b,l). Assignment scan over M GTs (LDS-staged),
// then all loss contributions; 6 partial sums reduced per-wave -> atomicAdd.
__global__ void loss_kernel(const float* __restrict__ boxes_xyxy,
                            const float* __restrict__ box_deltas,
                            const float* __restrict__ class_logits,
                            const float* __restrict__ objectness,
                            const float* __restrict__ centerness,
                            const float* __restrict__ locations,
                            const int* __restrict__ gt_labels,
                            const int* __restrict__ gh_p,
                            const int* __restrict__ gw_p,
                            int L, int M, int C, int bpb,
                            const float* __restrict__ info,
                            const int* __restrict__ flags,
                            float* __restrict__ accums) {
    __shared__ float s_x1[MAXM], s_y1[MAXM], s_x2[MAXM], s_y2[MAXM];
    __shared__ float s_cx[MAXM], s_cy[MAXM], s_area[MAXM];
    __shared__ int   s_lab[MAXM], s_hc[MAXM], s_best[MAXM];

    int b    = blockIdx.x / bpb;
    int lblk = blockIdx.x % bpb;
    int tid  = threadIdx.x;

    if (tid < M && tid < MAXM) {
        int bm = b * M + tid;
        const float* oi = info + (size_t)bm * 8;
        s_x1[tid] = oi[0]; s_y1[tid] = oi[1]; s_x2[tid] = oi[2]; s_y2[tid] = oi[3];
        s_cx[tid] = oi[4]; s_cy[tid] = oi[5]; s_area[tid] = oi[6];
        s_lab[tid]  = gt_labels[bm];
        s_hc[tid]   = flags[bm * 2];
        s_best[tid] = flags[bm * 2 + 1];
    }
    __syncthreads();

    int l = lblk * (int)blockDim.x + tid;
    float a_obj = 0.f, a_cls = 0.f, a_w = 0.f, a_l1 = 0.f, a_giou = 0.f, a_ctr = 0.f;

    if (l < L) {
        size_t bl = (size_t)b * L + l;
        float lx = locations[2 * l], ly = locations[2 * l + 1];
        float rx = POS_RADIUS_C / (float)gw_p[0];
        float ry = POS_RADIUS_C / (float)gh_p[0];

        float minc = INFINITY;
        int   asg  = -1;
        for (int m = 0; m < M; ++m) {
            bool cand;
            if (s_hc[m]) {
                cand = (lx > s_x1[m]) && (ly > s_y1[m]) && (lx < s_x2[m]) && (ly < s_y2[m])
                    && (fabsf(lx - s_cx[m]) <= rx) && (fabsf(ly - s_cy[m]) <= ry);
            } else {
                cand = (l == s_best[m]);
            }
            if (cand && (s_area[m] < minc)) { minc = s_area[m]; asg = m; }  // first-min wins
        }
        bool  pos   = (asg >= 0);
        float pos_f = pos ? 1.0f : 0.0f;

        // objectness focal (all locations)
        a_obj = focal_elem(objectness[bl], pos_f);

        // class focal (all locations x C classes)
        const float* cl = class_logits + bl * (size_t)C;
        int lab = pos ? s_lab[asg] : -1;
        float sc = 0.0f;
        if ((C & 3) == 0 && ((((size_t)cl) & 15) == 0)) {
            const float4* cl4 = (const float4*)cl;
            int n4 = C >> 2;
            for (int c4 = 0; c4 < n4; ++c4) {
                float4 v = cl4[c4];
                int c = c4 << 2;
                sc += focal_elem(v.x, (c     == lab) ? 1.f : 0.f);
                sc += focal_elem(v.y, (c + 1 == lab) ? 1.f : 0.f);
                sc += focal_elem(v.z, (c + 2 == lab) ? 1.f : 0.f);
                sc += focal_elem(v.w, (c + 3 == lab) ? 1.f : 0.f);
            }
        } else {
            for (int c = 0; c < C; ++c) sc += focal_elem(cl[c], (c == lab) ? 1.f : 0.f);
        }
        a_cls = sc;

        if (pos) {
            float ax1 = s_x1[asg], ay1 = s_y1[asg], ax2 = s_x2[asg], ay2 = s_y2[asg];
            float ltl = fmaxf(lx - ax1, 1e-6f);
            float ltt = fmaxf(ly - ay1, 1e-6f);
            float ltr = fmaxf(ax2 - lx, 1e-6f);
            float ltb = fmaxf(ay2 - ly, 1e-6f);
            float hor = fminf(ltl, ltr) / fmaxf(fmaxf(ltl, ltr), 1e-6f);
            float ver = fminf(ltt, ltb) / fmaxf(fmaxf(ltt, ltb), 1e-6f);
            float ctr_t = sqrtf(fmaxf(hor * ver, 0.0f));
            float wgt = fmaxf(ctr_t, 0.1f);
            a_w = wgt;

            // smooth-L1 (beta = 0.1), mean over 4 coords
            const float* bd = box_deltas + bl * 4;
            float tv0 = ltl, tv1 = ltt, tv2 = ltr, tv3 = ltb;
            float d0 = fabsf(bd[0] - tv0), d1 = fabsf(bd[1] - tv1);
            float d2 = fabsf(bd[2] - tv2), d3 = fabsf(bd[3] - tv3);
            float l1s = ((d0 < 0.1f) ? (0.5f * d0 * d0 / 0.1f) : (d0 - 0.05f))
                      + ((d1 < 0.1f) ? (0.5f * d1 * d1 / 0.1f) : (d1 - 0.05f))
                      + ((d2 < 0.1f) ? (0.5f * d2 * d2 / 0.1f) : (d2 - 0.05f))
                      + ((d3 < 0.1f) ? (0.5f * d3 * d3 / 0.1f) : (d3 - 0.05f));
            a_l1 = (l1s * 0.25f) * wgt;

            // GIoU
            const float* pb = boxes_xyxy + bl * 4;
            float px1 = pb[0], py1 = pb[1], px2 = pb[2], py2 = pb[3];
            float ilx = fmaxf(px1, ax1), ily = fmaxf(py1, ay1);
            float irx = fminf(px2, ax2), iry = fminf(py2, ay2);
            float iw = fmaxf(irx - ilx, 0.f), ih = fmaxf(iry - ily, 0.f);
            float inter = iw * ih;
            float ap = fmaxf(px2 - px1, 0.f) * fmaxf(py2 - py1, 0.f);
            float ag = fmaxf(ax2 - ax1, 0.f) * fmaxf(ay2 - ay1, 0.f);
            float un = ap + ag - inter;
            float iou = inter / fmaxf(un, 1e-6f);
            float hlx = fminf(px1, ax1), hly = fminf(py1, ay1);
            float hrx = fmaxf(px2, ax2), hry = fmaxf(py2, ay2);
            float hw = fmaxf(hrx - hlx, 0.f), hh = fmaxf(hry - hly, 0.f);
            float hull = hw * hh;
            float giou = iou - (hull - un) / fmaxf(hull, 1e-6f);
            a_giou = (1.0f - giou) * wgt;

            // centerness BCE
            float xc = centerness[bl];
            float bce = fmaxf(xc, 0.f) - xc * ctr_t + __logf(1.0f + __expf(-fabsf(xc)));
            a_ctr = bce * wgt;
        }
    }

    // wave (64-lane) shuffle reduction, then one atomicAdd per wave
    for (int off = 32; off > 0; off >>= 1) {
        a_obj  += __shfl_down(a_obj,  off);
        a_cls  += __shfl_down(a_cls,  off);
        a_w    += __shfl_down(a_w,    off);
        a_l1   += __shfl_down(a_l1,   off);
        a_giou += __shfl_down(a_giou, off);
        a_ctr  += __shfl_down(a_ctr,  off);
    }
    if ((tid & 63) == 0) {
        atomicAdd(&accums[0], a_obj);
        atomicAdd(&accums[1], a_cls);
        atomicAdd(&accums[2], a_w);
        atomicAdd(&accums[3], a_l1);
        atomicAdd(&accums[4], a_giou);
        atomicAdd(&accums[5], a_ctr);
    }
}

__global__ void finalize_kernel(const float* __restrict__ accums,
                                float* __restrict__ out,
                                float invBL, float invBLC) {
    float obj  = accums[0] * invBL;
    float cls  = accums[1] * invBLC;
    float wsum = accums[2];
    float l1   = accums[3] / wsum;
    float giou = accums[4] / wsum;
    float ctr  = accums[5] / wsum;
    out[0] = OBJ_W_C * obj + CTR_W_C * ctr + CLS_W_C * cls + BOX_W_C * l1 + GIOU_W_C * giou;
}

extern "C" void kernel_launch(void* const* d_in, const int* in_sizes, int n_in,
                              void* d_out, int out_size, void* d_ws, size_t ws_size,
                              hipStream_t stream) {
    const float* boxes_xyxy   = (const float*)d_in[0];
    const float* box_deltas   = (const float*)d_in[1];
    const float* class_logits = (const float*)d_in[2];
    const float* objectness   = (const float*)d_in[3];
    const float* centerness   = (const float*)d_in[4];
    const float* locations    = (const float*)d_in[5];
    const float* gt_boxes     = (const float*)d_in[6];
    const int*   gt_labels    = (const int*)d_in[7];
    const int*   gh           = (const int*)d_in[8];
    const int*   gw           = (const int*)d_in[9];

    int L = in_sizes[5] / 2;             // locations: (L,2)
    int B = in_sizes[3] / L;             // objectness: (B,L)
    int C = in_sizes[2] / in_sizes[3];   // class_logits: (B,L,C)
    int M = in_sizes[7] / B;             // gt_labels: (B,M)

    // workspace layout: [0,64): 8 float accumulators; then flags (B*M*2 ints,
    // 64B-aligned); then info (B*M*8 floats)
    float* accums = (float*)d_ws;
    int*   flags  = (int*)((char*)d_ws + 64);
    size_t flags_bytes = ((size_t)B * M * 2 * sizeof(int) + 63) / 64 * 64;
    float* info   = (float*)((char*)d_ws + 64 + flags_bytes);

    gt_assign_kernel<<<B * M, 256, 0, stream>>>(locations, gt_boxes, gh, gw,
                                                L, M, info, flags, accums);

    int bpb = (L + 255) / 256;
    loss_kernel<<<B * bpb, 256, 0, stream>>>(boxes_xyxy, box_deltas, class_logits,
                                             objectness, centerness, locations,
                                             gt_labels, gh, gw, L, M, C, bpb,
                                             info, flags, accums);

    float invBL  = (float)(1.0 / ((double)B * (double)L));
    float invBLC = (float)(1.0 / ((double)B * (double)L * (double)C));
    finalize_kernel<<<1, 1, 0, stream>>>(accums, (float*)d_out, invBL, invBLC);
}

// Round 2
// 267.204 us; speedup vs baseline: 1.9221x; 1.9221x over previous
//
#include <hip/hip_runtime.h>
#include <cstdint>
#include <cstddef>
#include <math.h>

#define BOX_W_C  5.0f
#define GIOU_W_C 2.0f
#define OBJ_W_C  1.0f
#define CLS_W_C  1.5f
#define CTR_W_C  0.5f
#define POS_RADIUS_C 1.0f
#define MAXM 128

// focal element: a_t * ce * (1-p_t)^2 with alpha=0.25, gamma=2, t in {0,1}
__device__ __forceinline__ float focal_elem(float x, float t) {
    float ax = fabsf(x);
    float e  = __expf(-ax);
    float lg = __logf(1.0f + e);              // log1p(exp(-|x|)), e in (0,1]
    float ce = fmaxf(x, 0.0f) - x * t + lg;
    float p  = (x >= 0.0f) ? (1.0f / (1.0f + e)) : (e / (1.0f + e));  // sigmoid
    float p_t = p * t + (1.0f - p) * (1.0f - t);
    float a_t = 0.25f * t + 0.75f * (1.0f - t);
    float om  = 1.0f - p_t;
    return a_t * ce * om * om;
}

// Kernel 1: one block per (b,m). Computes per-GT: x1,y1,x2,y2,cx,cy,area,
// has_candidate, and fallback best location (first-occurrence argmin,
// matching jnp.argmin semantics exactly).
__global__ void gt_assign_kernel(const float* __restrict__ locations,
                                 const float* __restrict__ gt_boxes,
                                 const int* __restrict__ gh_p,
                                 const int* __restrict__ gw_p,
                                 int L, int M,
                                 float* __restrict__ info,
                                 int* __restrict__ flags,
                                 float* __restrict__ accums) {
    int bm  = blockIdx.x;
    int tid = threadIdx.x;
    if (bm == 0 && tid < 8) accums[tid] = 0.0f;   // zero accumulators (ws is 0xAA-poisoned)

    const float* gb = gt_boxes + (size_t)bm * 4;
    float cx = gb[0], cy = gb[1], w = gb[2], h = gb[3];
    float x1 = cx - w * 0.5f, y1 = cy - h * 0.5f;
    float x2 = cx + w * 0.5f, y2 = cy + h * 0.5f;
    float area = w * h;
    float rx = POS_RADIUS_C / (float)gw_p[0];
    float ry = POS_RADIUS_C / (float)gh_p[0];

    float bin_v  = INFINITY; int bin_i  = 0x7fffffff;  // argmin dist | inside_box
    float ball_v = INFINITY; int ball_i = 0x7fffffff;  // argmin dist (unmasked)
    int any_cand = 0, any_in = 0;

    const float2* loc2 = (const float2*)locations;
    for (int l = tid; l < L; l += blockDim.x) {
        float2 p2 = loc2[l];
        float lx = p2.x, ly = p2.y;
        bool inb = (lx > x1) && (ly > y1) && (lx < x2) && (ly < y2);
        bool inc = (fabsf(lx - cx) <= rx) && (fabsf(ly - cy) <= ry);
        any_cand |= (int)(inb && inc);
        any_in   |= (int)inb;
        float dx = lx - cx, dy = ly - cy;
        float dist = dx * dx + dy * dy;
        if (dist < ball_v) { ball_v = dist; ball_i = l; }   // strict < keeps first occurrence
        float din = inb ? dist : INFINITY;
        if (din < bin_v) { bin_v = din; bin_i = l; }
    }

    __shared__ float s_v1[256]; __shared__ int s_i1[256];
    __shared__ float s_v2[256]; __shared__ int s_i2[256];
    __shared__ int s_c[256]; __shared__ int s_n[256];
    s_v1[tid] = bin_v;  s_i1[tid] = bin_i;
    s_v2[tid] = ball_v; s_i2[tid] = ball_i;
    s_c[tid] = any_cand; s_n[tid] = any_in;
    __syncthreads();
    for (int s = blockDim.x / 2; s > 0; s >>= 1) {
        if (tid < s) {
            if (s_v1[tid + s] < s_v1[tid] ||
                (s_v1[tid + s] == s_v1[tid] && s_i1[tid + s] < s_i1[tid])) {
                s_v1[tid] = s_v1[tid + s]; s_i1[tid] = s_i1[tid + s];
            }
            if (s_v2[tid + s] < s_v2[tid] ||
                (s_v2[tid + s] == s_v2[tid] && s_i2[tid + s] < s_i2[tid])) {
                s_v2[tid] = s_v2[tid + s]; s_i2[tid] = s_i2[tid + s];
            }
            s_c[tid] |= s_c[tid + s];
            s_n[tid] |= s_n[tid + s];
        }
        __syncthreads();
    }
    if (tid == 0) {
        int best = s_n[0] ? s_i1[0] : s_i2[0];
        flags[bm * 2]     = s_c[0];
        flags[bm * 2 + 1] = best;
        float* oi = info + (size_t)bm * 8;
        oi[0] = x1; oi[1] = y1; oi[2] = x2; oi[3] = y2;
        oi[4] = cx; oi[5] = cy; oi[6] = area; oi[7] = 0.0f;
    }
}

// Kernel 2: one thread per (b,l). Assignment scan over M GTs (LDS-staged),
// obj focal + box/GIoU/ctr losses. Writes lab[b*L+l] (int16, -1 = negative)
// for the coalesced class-focal kernel. Per-block LDS reduce -> 5 atomics.
__global__ void assign_loss_kernel(const float* __restrict__ boxes_xyxy,
                                   const float* __restrict__ box_deltas,
                                   const float* __restrict__ objectness,
                                   const float* __restrict__ centerness,
                                   const float* __restrict__ locations,
                                   const int* __restrict__ gt_labels,
                                   const int* __restrict__ gh_p,
                                   const int* __restrict__ gw_p,
                                   int L, int M, int bpb,
                                   const float* __restrict__ info,
                                   const int* __restrict__ flags,
                                   short* __restrict__ lab_out,
                                   float* __restrict__ accums) {
    __shared__ float s_x1[MAXM], s_y1[MAXM], s_x2[MAXM], s_y2[MAXM];
    __shared__ float s_cx[MAXM], s_cy[MAXM], s_area[MAXM];
    __shared__ int   s_lab[MAXM], s_hc[MAXM], s_best[MAXM];

    int b    = blockIdx.x / bpb;
    int lblk = blockIdx.x % bpb;
    int tid  = threadIdx.x;

    if (tid < M && tid < MAXM) {
        int bm = b * M + tid;
        const float* oi = info + (size_t)bm * 8;
        s_x1[tid] = oi[0]; s_y1[tid] = oi[1]; s_x2[tid] = oi[2]; s_y2[tid] = oi[3];
        s_cx[tid] = oi[4]; s_cy[tid] = oi[5]; s_area[tid] = oi[6];
        s_lab[tid]  = gt_labels[bm];
        s_hc[tid]   = flags[bm * 2];
        s_best[tid] = flags[bm * 2 + 1];
    }
    __syncthreads();

    int l = lblk * (int)blockDim.x + tid;
    float a_obj = 0.f, a_w = 0.f, a_l1 = 0.f, a_giou = 0.f, a_ctr = 0.f;

    if (l < L) {
        size_t bl = (size_t)b * L + l;
        const float2* loc2 = (const float2*)locations;
        float2 p2 = loc2[l];
        float lx = p2.x, ly = p2.y;
        float rx = POS_RADIUS_C / (float)gw_p[0];
        float ry = POS_RADIUS_C / (float)gh_p[0];

        float minc = INFINITY;
        int   asg  = -1;
        for (int m = 0; m < M; ++m) {
            bool cand;
            if (s_hc[m]) {
                cand = (lx > s_x1[m]) && (ly > s_y1[m]) && (lx < s_x2[m]) && (ly < s_y2[m])
                    && (fabsf(lx - s_cx[m]) <= rx) && (fabsf(ly - s_cy[m]) <= ry);
            } else {
                cand = (l == s_best[m]);
            }
            if (cand && (s_area[m] < minc)) { minc = s_area[m]; asg = m; }  // first-min wins
        }
        bool  pos   = (asg >= 0);
        float pos_f = pos ? 1.0f : 0.0f;

        lab_out[bl] = pos ? (short)s_lab[asg] : (short)-1;

        a_obj = focal_elem(objectness[bl], pos_f);

        if (pos) {
            float ax1 = s_x1[asg], ay1 = s_y1[asg], ax2 = s_x2[asg], ay2 = s_y2[asg];
            float ltl = fmaxf(lx - ax1, 1e-6f);
            float ltt = fmaxf(ly - ay1, 1e-6f);
            float ltr = fmaxf(ax2 - lx, 1e-6f);
            float ltb = fmaxf(ay2 - ly, 1e-6f);
            float hor = fminf(ltl, ltr) / fmaxf(fmaxf(ltl, ltr), 1e-6f);
            float ver = fminf(ltt, ltb) / fmaxf(fmaxf(ltt, ltb), 1e-6f);
            float ctr_t = sqrtf(fmaxf(hor * ver, 0.0f));
            float wgt = fmaxf(ctr_t, 0.1f);
            a_w = wgt;

            // smooth-L1 (beta = 0.1), mean over 4 coords
            const float4 bd = *(const float4*)(box_deltas + bl * 4);
            float d0 = fabsf(bd.x - ltl), d1 = fabsf(bd.y - ltt);
            float d2 = fabsf(bd.z - ltr), d3 = fabsf(bd.w - ltb);
            float l1s = ((d0 < 0.1f) ? (0.5f * d0 * d0 / 0.1f) : (d0 - 0.05f))
                      + ((d1 < 0.1f) ? (0.5f * d1 * d1 / 0.1f) : (d1 - 0.05f))
                      + ((d2 < 0.1f) ? (0.5f * d2 * d2 / 0.1f) : (d2 - 0.05f))
                      + ((d3 < 0.1f) ? (0.5f * d3 * d3 / 0.1f) : (d3 - 0.05f));
            a_l1 = (l1s * 0.25f) * wgt;

            // GIoU
            const float4 pb = *(const float4*)(boxes_xyxy + bl * 4);
            float px1 = pb.x, py1 = pb.y, px2 = pb.z, py2 = pb.w;
            float ilx = fmaxf(px1, ax1), ily = fmaxf(py1, ay1);
            float irx = fminf(px2, ax2), iry = fminf(py2, ay2);
            float iw = fmaxf(irx - ilx, 0.f), ih = fmaxf(iry - ily, 0.f);
            float inter = iw * ih;
            float ap = fmaxf(px2 - px1, 0.f) * fmaxf(py2 - py1, 0.f);
            float ag = fmaxf(ax2 - ax1, 0.f) * fmaxf(ay2 - ay1, 0.f);
            float un = ap + ag - inter;
            float iou = inter / fmaxf(un, 1e-6f);
            float hlx = fminf(px1, ax1), hly = fminf(py1, ay1);
            float hrx = fmaxf(px2, ax2), hry = fmaxf(py2, ay2);
            float hw = fmaxf(hrx - hlx, 0.f), hh = fmaxf(hry - hly, 0.f);
            float hull = hw * hh;
            float giou = iou - (hull - un) / fmaxf(hull, 1e-6f);
            a_giou = (1.0f - giou) * wgt;

            // centerness BCE
            float xc = centerness[bl];
            float bce = fmaxf(xc, 0.f) - xc * ctr_t + __logf(1.0f + __expf(-fabsf(xc)));
            a_ctr = bce * wgt;
        }
    }

    // wave shuffle reduce (64 lanes), LDS across waves, one atomic set per block
    for (int off = 32; off > 0; off >>= 1) {
        a_obj  += __shfl_down(a_obj,  off);
        a_w    += __shfl_down(a_w,    off);
        a_l1   += __shfl_down(a_l1,   off);
        a_giou += __shfl_down(a_giou, off);
        a_ctr  += __shfl_down(a_ctr,  off);
    }
    __shared__ float red[4][5];
    int wid = tid >> 6;
    if ((tid & 63) == 0) {
        red[wid][0] = a_obj; red[wid][1] = a_w; red[wid][2] = a_l1;
        red[wid][3] = a_giou; red[wid][4] = a_ctr;
    }
    __syncthreads();
    if (tid == 0) {
        int nw = (int)blockDim.x >> 6;
        float r0 = 0.f, r1 = 0.f, r2 = 0.f, r3 = 0.f, r4 = 0.f;
        for (int w2 = 0; w2 < nw; ++w2) {
            r0 += red[w2][0]; r1 += red[w2][1]; r2 += red[w2][2];
            r3 += red[w2][3]; r4 += red[w2][4];
        }
        atomicAdd(&accums[0], r0);
        atomicAdd(&accums[2], r1);
        atomicAdd(&accums[3], r2);
        atomicAdd(&accums[4], r3);
        atomicAdd(&accums[5], r4);
    }
}

// Kernel 3: class focal, fully coalesced. Grid-stride over float4 chunks of
// class_logits (requires C % 4 == 0). target = (c == lab[loc]).
__global__ void cls_focal4_kernel(const float* __restrict__ class_logits,
                                  const short* __restrict__ lab,
                                  int total4, int C4,
                                  float* __restrict__ accums) {
    const float4* cl4 = (const float4*)class_logits;
    int stride = (int)(gridDim.x * blockDim.x);
    float s = 0.f;
    for (int i = (int)(blockIdx.x * blockDim.x + threadIdx.x); i < total4; i += stride) {
        int loc = i / C4;
        int c0  = (i - loc * C4) << 2;
        int lv  = (int)lab[loc];
        float4 v = cl4[i];
        s += focal_elem(v.x, (c0     == lv) ? 1.f : 0.f);
        s += focal_elem(v.y, (c0 + 1 == lv) ? 1.f : 0.f);
        s += focal_elem(v.z, (c0 + 2 == lv) ? 1.f : 0.f);
        s += focal_elem(v.w, (c0 + 3 == lv) ? 1.f : 0.f);
    }
    for (int off = 32; off > 0; off >>= 1) s += __shfl_down(s, off);
    __shared__ float sw[4];
    int wid = threadIdx.x >> 6;
    if ((threadIdx.x & 63) == 0) sw[wid] = s;
    __syncthreads();
    if (threadIdx.x == 0) {
        int nw = (int)blockDim.x >> 6;
        float t = 0.f;
        for (int w2 = 0; w2 < nw; ++w2) t += sw[w2];
        atomicAdd(&accums[1], t);
    }
}

// Scalar fallback for C % 4 != 0 (not hit at current shapes).
__global__ void cls_focal1_kernel(const float* __restrict__ class_logits,
                                  const short* __restrict__ lab,
                                  long total, int C,
                                  float* __restrict__ accums) {
    long stride = (long)gridDim.x * blockDim.x;
    float s = 0.f;
    for (long i = (long)blockIdx.x * blockDim.x + threadIdx.x; i < total; i += stride) {
        long loc = i / C;
        int c = (int)(i - loc * C);
        int lv = (int)lab[loc];
        s += focal_elem(class_logits[i], (c == lv) ? 1.f : 0.f);
    }
    for (int off = 32; off > 0; off >>= 1) s += __shfl_down(s, off);
    __shared__ float sw[4];
    int wid = threadIdx.x >> 6;
    if ((threadIdx.x & 63) == 0) sw[wid] = s;
    __syncthreads();
    if (threadIdx.x == 0) {
        int nw = (int)blockDim.x >> 6;
        float t = 0.f;
        for (int w2 = 0; w2 < nw; ++w2) t += sw[w2];
        atomicAdd(&accums[1], t);
    }
}

__global__ void finalize_kernel(const float* __restrict__ accums,
                                float* __restrict__ out,
                                float invBL, float invBLC) {
    float obj  = accums[0] * invBL;
    float cls  = accums[1] * invBLC;
    float wsum = accums[2];
    float l1   = accums[3] / wsum;
    float giou = accums[4] / wsum;
    float ctr  = accums[5] / wsum;
    out[0] = OBJ_W_C * obj + CTR_W_C * ctr + CLS_W_C * cls + BOX_W_C * l1 + GIOU_W_C * giou;
}

extern "C" void kernel_launch(void* const* d_in, const int* in_sizes, int n_in,
                              void* d_out, int out_size, void* d_ws, size_t ws_size,
                              hipStream_t stream) {
    const float* boxes_xyxy   = (const float*)d_in[0];
    const float* box_deltas   = (const float*)d_in[1];
    const float* class_logits = (const float*)d_in[2];
    const float* objectness   = (const float*)d_in[3];
    const float* centerness   = (const float*)d_in[4];
    const float* locations    = (const float*)d_in[5];
    const float* gt_boxes     = (const float*)d_in[6];
    const int*   gt_labels    = (const int*)d_in[7];
    const int*   gh           = (const int*)d_in[8];
    const int*   gw           = (const int*)d_in[9];

    int L = in_sizes[5] / 2;             // locations: (L,2)
    int B = in_sizes[3] / L;             // objectness: (B,L)
    int C = in_sizes[2] / in_sizes[3];   // class_logits: (B,L,C)
    int M = in_sizes[7] / B;             // gt_labels: (B,M)

    // ws layout: [0,64) accums (8 floats) | lab (B*L int16, 64B-aligned)
    //            | flags (B*M*2 int) | info (B*M*8 float)
    float* accums = (float*)d_ws;
    short* lab    = (short*)((char*)d_ws + 64);
    size_t lab_bytes   = ((size_t)B * L * sizeof(short) + 63) / 64 * 64;
    int*   flags  = (int*)((char*)d_ws + 64 + lab_bytes);
    size_t flags_bytes = ((size_t)B * M * 2 * sizeof(int) + 63) / 64 * 64;
    float* info   = (float*)((char*)d_ws + 64 + lab_bytes + flags_bytes);

    gt_assign_kernel<<<B * M, 256, 0, stream>>>(locations, gt_boxes, gh, gw,
                                                L, M, info, flags, accums);

    int bpb = (L + 255) / 256;
    assign_loss_kernel<<<B * bpb, 256, 0, stream>>>(boxes_xyxy, box_deltas,
                                                    objectness, centerness,
                                                    locations, gt_labels, gh, gw,
                                                    L, M, bpb, info, flags,
                                                    lab, accums);

    size_t total = (size_t)B * L * C;
    if ((C & 3) == 0 && total / 4 <= 0x7fffffff) {
        int total4 = (int)(total / 4);
        int blocks = (total4 + 255) / 256;
        if (blocks > 2048) blocks = 2048;
        cls_focal4_kernel<<<blocks, 256, 0, stream>>>(class_logits, lab,
                                                      total4, C >> 2, accums);
    } else {
        cls_focal1_kernel<<<2048, 256, 0, stream>>>(class_logits, lab,
                                                    (long)total, C, accums);
    }

    float invBL  = (float)(1.0 / ((double)B * (double)L));
    float invBLC = (float)(1.0 / ((double)B * (double)L * (double)C));
    finalize_kernel<<<1, 1, 0, stream>>>(accums, (float*)d_out, invBL, invBLC);
}

// Round 3
// 181.593 us; speedup vs baseline: 2.8282x; 1.4714x over previous
//
#include <hip/hip_runtime.h>
#include <cstdint>
#include <cstddef>
#include <math.h>

#define BOX_W_C  5.0f
#define GIOU_W_C 2.0f
#define OBJ_W_C  1.0f
#define CLS_W_C  1.5f
#define CTR_W_C  0.5f
#define POS_RADIUS_C 1.0f
#define MAXM 128
#define CLS_BLOCKS 2048

// focal element: a_t * ce * (1-p_t)^2 with alpha=0.25, gamma=2, t in {0,1}
__device__ __forceinline__ float focal_elem(float x, float t) {
    float ax = fabsf(x);
    float e  = __expf(-ax);
    float lg = __logf(1.0f + e);              // log1p(exp(-|x|)), e in (0,1]
    float ce = fmaxf(x, 0.0f) - x * t + lg;
    float p  = (x >= 0.0f) ? (1.0f / (1.0f + e)) : (e / (1.0f + e));  // sigmoid
    float p_t = p * t + (1.0f - p) * (1.0f - t);
    float a_t = 0.25f * t + 0.75f * (1.0f - t);
    float om  = 1.0f - p_t;
    return a_t * ce * om * om;
}

// Kernel 1: one block per (b,m). Per-GT: box coords, area, has_candidate,
// fallback best location (first-occurrence argmin, jnp.argmin semantics).
__global__ void gt_assign_kernel(const float* __restrict__ locations,
                                 const float* __restrict__ gt_boxes,
                                 const int* __restrict__ gh_p,
                                 const int* __restrict__ gw_p,
                                 int L, int M,
                                 float* __restrict__ info,
                                 int* __restrict__ flags) {
    int bm  = blockIdx.x;
    int tid = threadIdx.x;

    const float* gb = gt_boxes + (size_t)bm * 4;
    float cx = gb[0], cy = gb[1], w = gb[2], h = gb[3];
    float x1 = cx - w * 0.5f, y1 = cy - h * 0.5f;
    float x2 = cx + w * 0.5f, y2 = cy + h * 0.5f;
    float area = w * h;
    float rx = POS_RADIUS_C / (float)gw_p[0];
    float ry = POS_RADIUS_C / (float)gh_p[0];

    float bin_v  = INFINITY; int bin_i  = 0x7fffffff;  // argmin dist | inside_box
    float ball_v = INFINITY; int ball_i = 0x7fffffff;  // argmin dist (unmasked)
    int any_cand = 0, any_in = 0;

    const float2* loc2 = (const float2*)locations;
    for (int l = tid; l < L; l += blockDim.x) {
        float2 p2 = loc2[l];
        float lx = p2.x, ly = p2.y;
        bool inb = (lx > x1) && (ly > y1) && (lx < x2) && (ly < y2);
        bool inc = (fabsf(lx - cx) <= rx) && (fabsf(ly - cy) <= ry);
        any_cand |= (int)(inb && inc);
        any_in   |= (int)inb;
        float dx = lx - cx, dy = ly - cy;
        float dist = dx * dx + dy * dy;
        if (dist < ball_v) { ball_v = dist; ball_i = l; }   // strict < keeps first occurrence
        float din = inb ? dist : INFINITY;
        if (din < bin_v) { bin_v = din; bin_i = l; }
    }

    __shared__ float s_v1[512]; __shared__ int s_i1[512];
    __shared__ float s_v2[512]; __shared__ int s_i2[512];
    __shared__ int s_c[512]; __shared__ int s_n[512];
    s_v1[tid] = bin_v;  s_i1[tid] = bin_i;
    s_v2[tid] = ball_v; s_i2[tid] = ball_i;
    s_c[tid] = any_cand; s_n[tid] = any_in;
    __syncthreads();
    for (int s = blockDim.x / 2; s > 0; s >>= 1) {
        if (tid < s) {
            if (s_v1[tid + s] < s_v1[tid] ||
                (s_v1[tid + s] == s_v1[tid] && s_i1[tid + s] < s_i1[tid])) {
                s_v1[tid] = s_v1[tid + s]; s_i1[tid] = s_i1[tid + s];
            }
            if (s_v2[tid + s] < s_v2[tid] ||
                (s_v2[tid + s] == s_v2[tid] && s_i2[tid + s] < s_i2[tid])) {
                s_v2[tid] = s_v2[tid + s]; s_i2[tid] = s_i2[tid + s];
            }
            s_c[tid] |= s_c[tid + s];
            s_n[tid] |= s_n[tid + s];
        }
        __syncthreads();
    }
    if (tid == 0) {
        int best = s_n[0] ? s_i1[0] : s_i2[0];
        flags[bm * 2]     = s_c[0];
        flags[bm * 2 + 1] = best;
        float* oi = info + (size_t)bm * 8;
        oi[0] = x1; oi[1] = y1; oi[2] = x2; oi[3] = y2;
        oi[4] = cx; oi[5] = cy; oi[6] = area; oi[7] = 0.0f;
    }
}

// Kernel 2: one thread per (b,l). Assignment scan over M GTs (LDS-staged),
// obj focal + box/GIoU/ctr losses. Writes lab[b*L+l] (int16, -1 = negative).
// NO atomics: per-block partials stored to private slots (SoA layout).
__global__ void assign_loss_kernel(const float* __restrict__ boxes_xyxy,
                                   const float* __restrict__ box_deltas,
                                   const float* __restrict__ objectness,
                                   const float* __restrict__ centerness,
                                   const float* __restrict__ locations,
                                   const int* __restrict__ gt_labels,
                                   const int* __restrict__ gh_p,
                                   const int* __restrict__ gw_p,
                                   int L, int M, int bpb, int nblk,
                                   const float* __restrict__ info,
                                   const int* __restrict__ flags,
                                   short* __restrict__ lab_out,
                                   float* __restrict__ partials) {
    __shared__ float s_x1[MAXM], s_y1[MAXM], s_x2[MAXM], s_y2[MAXM];
    __shared__ float s_cx[MAXM], s_cy[MAXM], s_area[MAXM];
    __shared__ int   s_lab[MAXM], s_hc[MAXM], s_best[MAXM];

    int b    = blockIdx.x / bpb;
    int lblk = blockIdx.x % bpb;
    int tid  = threadIdx.x;

    if (tid < M && tid < MAXM) {
        int bm = b * M + tid;
        const float* oi = info + (size_t)bm * 8;
        s_x1[tid] = oi[0]; s_y1[tid] = oi[1]; s_x2[tid] = oi[2]; s_y2[tid] = oi[3];
        s_cx[tid] = oi[4]; s_cy[tid] = oi[5]; s_area[tid] = oi[6];
        s_lab[tid]  = gt_labels[bm];
        s_hc[tid]   = flags[bm * 2];
        s_best[tid] = flags[bm * 2 + 1];
    }
    __syncthreads();

    int l = lblk * (int)blockDim.x + tid;
    float a_obj = 0.f, a_w = 0.f, a_l1 = 0.f, a_giou = 0.f, a_ctr = 0.f;

    if (l < L) {
        size_t bl = (size_t)b * L + l;
        const float2* loc2 = (const float2*)locations;
        float2 p2 = loc2[l];
        float lx = p2.x, ly = p2.y;
        float rx = POS_RADIUS_C / (float)gw_p[0];
        float ry = POS_RADIUS_C / (float)gh_p[0];

        float minc = INFINITY;
        int   asg  = -1;
        for (int m = 0; m < M; ++m) {
            bool cand;
            if (s_hc[m]) {
                cand = (lx > s_x1[m]) && (ly > s_y1[m]) && (lx < s_x2[m]) && (ly < s_y2[m])
                    && (fabsf(lx - s_cx[m]) <= rx) && (fabsf(ly - s_cy[m]) <= ry);
            } else {
                cand = (l == s_best[m]);
            }
            if (cand && (s_area[m] < minc)) { minc = s_area[m]; asg = m; }  // first-min wins
        }
        bool  pos   = (asg >= 0);
        float pos_f = pos ? 1.0f : 0.0f;

        lab_out[bl] = pos ? (short)s_lab[asg] : (short)-1;

        a_obj = focal_elem(objectness[bl], pos_f);

        if (pos) {
            float ax1 = s_x1[asg], ay1 = s_y1[asg], ax2 = s_x2[asg], ay2 = s_y2[asg];
            float ltl = fmaxf(lx - ax1, 1e-6f);
            float ltt = fmaxf(ly - ay1, 1e-6f);
            float ltr = fmaxf(ax2 - lx, 1e-6f);
            float ltb = fmaxf(ay2 - ly, 1e-6f);
            float hor = fminf(ltl, ltr) / fmaxf(fmaxf(ltl, ltr), 1e-6f);
            float ver = fminf(ltt, ltb) / fmaxf(fmaxf(ltt, ltb), 1e-6f);
            float ctr_t = sqrtf(fmaxf(hor * ver, 0.0f));
            float wgt = fmaxf(ctr_t, 0.1f);
            a_w = wgt;

            // smooth-L1 (beta = 0.1), mean over 4 coords
            const float4 bd = *(const float4*)(box_deltas + bl * 4);
            float d0 = fabsf(bd.x - ltl), d1 = fabsf(bd.y - ltt);
            float d2 = fabsf(bd.z - ltr), d3 = fabsf(bd.w - ltb);
            float l1s = ((d0 < 0.1f) ? (0.5f * d0 * d0 / 0.1f) : (d0 - 0.05f))
                      + ((d1 < 0.1f) ? (0.5f * d1 * d1 / 0.1f) : (d1 - 0.05f))
                      + ((d2 < 0.1f) ? (0.5f * d2 * d2 / 0.1f) : (d2 - 0.05f))
                      + ((d3 < 0.1f) ? (0.5f * d3 * d3 / 0.1f) : (d3 - 0.05f));
            a_l1 = (l1s * 0.25f) * wgt;

            // GIoU
            const float4 pb = *(const float4*)(boxes_xyxy + bl * 4);
            float px1 = pb.x, py1 = pb.y, px2 = pb.z, py2 = pb.w;
            float ilx = fmaxf(px1, ax1), ily = fmaxf(py1, ay1);
            float irx = fminf(px2, ax2), iry = fminf(py2, ay2);
            float iw = fmaxf(irx - ilx, 0.f), ih = fmaxf(iry - ily, 0.f);
            float inter = iw * ih;
            float ap = fmaxf(px2 - px1, 0.f) * fmaxf(py2 - py1, 0.f);
            float ag = fmaxf(ax2 - ax1, 0.f) * fmaxf(ay2 - ay1, 0.f);
            float un = ap + ag - inter;
            float iou = inter / fmaxf(un, 1e-6f);
            float hlx = fminf(px1, ax1), hly = fminf(py1, ay1);
            float hrx = fmaxf(px2, ax2), hry = fmaxf(py2, ay2);
            float hw = fmaxf(hrx - hlx, 0.f), hh = fmaxf(hry - hly, 0.f);
            float hull = hw * hh;
            float giou = iou - (hull - un) / fmaxf(hull, 1e-6f);
            a_giou = (1.0f - giou) * wgt;

            // centerness BCE
            float xc = centerness[bl];
            float bce = fmaxf(xc, 0.f) - xc * ctr_t + __logf(1.0f + __expf(-fabsf(xc)));
            a_ctr = bce * wgt;
        }
    }

    // wave shuffle reduce, LDS across waves, thread 0 stores 5 partials
    for (int off = 32; off > 0; off >>= 1) {
        a_obj  += __shfl_down(a_obj,  off);
        a_w    += __shfl_down(a_w,    off);
        a_l1   += __shfl_down(a_l1,   off);
        a_giou += __shfl_down(a_giou, off);
        a_ctr  += __shfl_down(a_ctr,  off);
    }
    __shared__ float red[4][5];
    int wid = tid >> 6;
    if ((tid & 63) == 0) {
        red[wid][0] = a_obj; red[wid][1] = a_w; red[wid][2] = a_l1;
        red[wid][3] = a_giou; red[wid][4] = a_ctr;
    }
    __syncthreads();
    if (tid == 0) {
        int nw = (int)blockDim.x >> 6;
        float r0 = 0.f, r1 = 0.f, r2 = 0.f, r3 = 0.f, r4 = 0.f;
        for (int w2 = 0; w2 < nw; ++w2) {
            r0 += red[w2][0]; r1 += red[w2][1]; r2 += red[w2][2];
            r3 += red[w2][3]; r4 += red[w2][4];
        }
        int blk = (int)blockIdx.x;
        partials[0 * nblk + blk] = r0;   // obj
        partials[1 * nblk + blk] = r1;   // wsum
        partials[2 * nblk + blk] = r2;   // l1
        partials[3 * nblk + blk] = r3;   // giou
        partials[4 * nblk + blk] = r4;   // ctr
    }
}

// Kernel 3: class focal, fully coalesced float4 grid-stride. No atomics —
// one partial store per block.
__global__ void cls_focal4_kernel(const float* __restrict__ class_logits,
                                  const short* __restrict__ lab,
                                  int total4, int C4,
                                  float* __restrict__ cls_partials) {
    const float4* cl4 = (const float4*)class_logits;
    int stride = (int)(gridDim.x * blockDim.x);
    float s = 0.f;
    for (int i = (int)(blockIdx.x * blockDim.x + threadIdx.x); i < total4; i += stride) {
        int loc = i / C4;
        int c0  = (i - loc * C4) << 2;
        int lv  = (int)lab[loc];
        float4 v = cl4[i];
        s += focal_elem(v.x, (c0     == lv) ? 1.f : 0.f);
        s += focal_elem(v.y, (c0 + 1 == lv) ? 1.f : 0.f);
        s += focal_elem(v.z, (c0 + 2 == lv) ? 1.f : 0.f);
        s += focal_elem(v.w, (c0 + 3 == lv) ? 1.f : 0.f);
    }
    for (int off = 32; off > 0; off >>= 1) s += __shfl_down(s, off);
    __shared__ float sw[4];
    int wid = threadIdx.x >> 6;
    if ((threadIdx.x & 63) == 0) sw[wid] = s;
    __syncthreads();
    if (threadIdx.x == 0) {
        int nw = (int)blockDim.x >> 6;
        float t = 0.f;
        for (int w2 = 0; w2 < nw; ++w2) t += sw[w2];
        cls_partials[blockIdx.x] = t;
    }
}

// Scalar fallback for C % 4 != 0 (not hit at current shapes).
__global__ void cls_focal1_kernel(const float* __restrict__ class_logits,
                                  const short* __restrict__ lab,
                                  long total, int C,
                                  float* __restrict__ cls_partials) {
    long stride = (long)gridDim.x * blockDim.x;
    float s = 0.f;
    for (long i = (long)blockIdx.x * blockDim.x + threadIdx.x; i < total; i += stride) {
        long loc = i / C;
        int c = (int)(i - loc * C);
        int lv = (int)lab[loc];
        s += focal_elem(class_logits[i], (c == lv) ? 1.f : 0.f);
    }
    for (int off = 32; off > 0; off >>= 1) s += __shfl_down(s, off);
    __shared__ float sw[4];
    int wid = threadIdx.x >> 6;
    if ((threadIdx.x & 63) == 0) sw[wid] = s;
    __syncthreads();
    if (threadIdx.x == 0) {
        int nw = (int)blockDim.x >> 6;
        float t = 0.f;
        for (int w2 = 0; w2 < nw; ++w2) t += sw[w2];
        cls_partials[blockIdx.x] = t;
    }
}

// Kernel 4: single-block deterministic reduction over all partials + combine.
__global__ void finalize_kernel(const float* __restrict__ partials, int nblk,
                                const float* __restrict__ cls_partials, int ncls,
                                float* __restrict__ out,
                                float invBL, float invBLC) {
    int tid = threadIdx.x;
    float r[5] = {0.f, 0.f, 0.f, 0.f, 0.f};
    for (int i = tid; i < nblk; i += blockDim.x) {
        r[0] += partials[0 * nblk + i];
        r[1] += partials[1 * nblk + i];
        r[2] += partials[2 * nblk + i];
        r[3] += partials[3 * nblk + i];
        r[4] += partials[4 * nblk + i];
    }
    float rc = 0.f;
    for (int i = tid; i < ncls; i += blockDim.x) rc += cls_partials[i];

    __shared__ float red[256][6];
    red[tid][0] = r[0]; red[tid][1] = r[1]; red[tid][2] = r[2];
    red[tid][3] = r[3]; red[tid][4] = r[4]; red[tid][5] = rc;
    __syncthreads();
    for (int s = (int)blockDim.x / 2; s > 0; s >>= 1) {
        if (tid < s) {
            for (int j = 0; j < 6; ++j) red[tid][j] += red[tid + s][j];
        }
        __syncthreads();
    }
    if (tid == 0) {
        float obj  = red[0][0] * invBL;
        float wsum = red[0][1];
        float l1   = red[0][2] / wsum;
        float giou = red[0][3] / wsum;
        float ctr  = red[0][4] / wsum;
        float cls  = red[0][5] * invBLC;
        out[0] = OBJ_W_C * obj + CTR_W_C * ctr + CLS_W_C * cls + BOX_W_C * l1 + GIOU_W_C * giou;
    }
}

extern "C" void kernel_launch(void* const* d_in, const int* in_sizes, int n_in,
                              void* d_out, int out_size, void* d_ws, size_t ws_size,
                              hipStream_t stream) {
    const float* boxes_xyxy   = (const float*)d_in[0];
    const float* box_deltas   = (const float*)d_in[1];
    const float* class_logits = (const float*)d_in[2];
    const float* objectness   = (const float*)d_in[3];
    const float* centerness   = (const float*)d_in[4];
    const float* locations    = (const float*)d_in[5];
    const float* gt_boxes     = (const float*)d_in[6];
    const int*   gt_labels    = (const int*)d_in[7];
    const int*   gh           = (const int*)d_in[8];
    const int*   gw           = (const int*)d_in[9];

    int L = in_sizes[5] / 2;             // locations: (L,2)
    int B = in_sizes[3] / L;             // objectness: (B,L)
    int C = in_sizes[2] / in_sizes[3];   // class_logits: (B,L,C)
    int M = in_sizes[7] / B;             // gt_labels: (B,M)

    int bpb  = (L + 255) / 256;
    int nblk = B * bpb;

    // ws layout (all 64B-aligned):
    //   lab      : B*L int16
    //   flags    : B*M*2 int
    //   info     : B*M*8 float
    //   partials : 5*nblk float   (assign_loss per-block sums, SoA)
    //   cls_part : CLS_BLOCKS float
    char* p = (char*)d_ws;
    short* lab    = (short*)p;            p += ((size_t)B * L * sizeof(short) + 63) / 64 * 64;
    int*   flags  = (int*)p;              p += ((size_t)B * M * 2 * sizeof(int) + 63) / 64 * 64;
    float* info   = (float*)p;            p += ((size_t)B * M * 8 * sizeof(float) + 63) / 64 * 64;
    float* partials = (float*)p;          p += ((size_t)5 * nblk * sizeof(float) + 63) / 64 * 64;
    float* cls_partials = (float*)p;

    gt_assign_kernel<<<B * M, 512, 0, stream>>>(locations, gt_boxes, gh, gw,
                                                L, M, info, flags);

    assign_loss_kernel<<<nblk, 256, 0, stream>>>(boxes_xyxy, box_deltas,
                                                 objectness, centerness,
                                                 locations, gt_labels, gh, gw,
                                                 L, M, bpb, nblk, info, flags,
                                                 lab, partials);

    size_t total = (size_t)B * L * C;
    int ncls;
    if ((C & 3) == 0 && total / 4 <= 0x7fffffff) {
        int total4 = (int)(total / 4);
        ncls = (total4 + 255) / 256;
        if (ncls > CLS_BLOCKS) ncls = CLS_BLOCKS;
        cls_focal4_kernel<<<ncls, 256, 0, stream>>>(class_logits, lab,
                                                    total4, C >> 2, cls_partials);
    } else {
        ncls = CLS_BLOCKS;
        cls_focal1_kernel<<<ncls, 256, 0, stream>>>(class_logits, lab,
                                                    (long)total, C, cls_partials);
    }

    float invBL  = (float)(1.0 / ((double)B * (double)L));
    float invBLC = (float)(1.0 / ((double)B * (double)L * (double)C));
    finalize_kernel<<<1, 256, 0, stream>>>(partials, nblk, cls_partials, ncls,
                                           (float*)d_out, invBL, invBLC);
}

// Round 4
// 179.678 us; speedup vs baseline: 2.8584x; 1.0107x over previous
//
#include <hip/hip_runtime.h>
#include <cstdint>
#include <cstddef>
#include <math.h>

#define BOX_W_C  5.0f
#define GIOU_W_C 2.0f
#define OBJ_W_C  1.0f
#define CLS_W_C  1.5f
#define CTR_W_C  0.5f
#define POS_RADIUS_C 1.0f
#define MAXM 128
#define BLK 256

// focal element: a_t * ce * (1-p_t)^2 with alpha=0.25, gamma=2, t in {0,1}
__device__ __forceinline__ float focal_elem(float x, float t) {
    float ax = fabsf(x);
    float e  = __expf(-ax);
    float lg = __logf(1.0f + e);              // log1p(exp(-|x|)), e in (0,1]
    float ce = fmaxf(x, 0.0f) - x * t + lg;
    float p  = (x >= 0.0f) ? (1.0f / (1.0f + e)) : (e / (1.0f + e));  // sigmoid
    float p_t = p * t + (1.0f - p) * (1.0f - t);
    float a_t = 0.25f * t + 0.75f * (1.0f - t);
    float om  = 1.0f - p_t;
    return a_t * ce * om * om;
}

// Kernel 1: one block per (b,m). Per-GT: box coords, area, has_candidate,
// fallback best location (first-occurrence argmin, jnp.argmin semantics).
__global__ void gt_assign_kernel(const float* __restrict__ locations,
                                 const float* __restrict__ gt_boxes,
                                 const int* __restrict__ gh_p,
                                 const int* __restrict__ gw_p,
                                 int L, int M,
                                 float* __restrict__ info,
                                 int* __restrict__ flags) {
    int bm  = blockIdx.x;
    int tid = threadIdx.x;

    const float* gb = gt_boxes + (size_t)bm * 4;
    float cx = gb[0], cy = gb[1], w = gb[2], h = gb[3];
    float x1 = cx - w * 0.5f, y1 = cy - h * 0.5f;
    float x2 = cx + w * 0.5f, y2 = cy + h * 0.5f;
    float area = w * h;
    float rx = POS_RADIUS_C / (float)gw_p[0];
    float ry = POS_RADIUS_C / (float)gh_p[0];

    float bin_v  = INFINITY; int bin_i  = 0x7fffffff;  // argmin dist | inside_box
    float ball_v = INFINITY; int ball_i = 0x7fffffff;  // argmin dist (unmasked)
    int any_cand = 0, any_in = 0;

    const float2* loc2 = (const float2*)locations;
    for (int l = tid; l < L; l += blockDim.x) {
        float2 p2 = loc2[l];
        float lx = p2.x, ly = p2.y;
        bool inb = (lx > x1) && (ly > y1) && (lx < x2) && (ly < y2);
        bool inc = (fabsf(lx - cx) <= rx) && (fabsf(ly - cy) <= ry);
        any_cand |= (int)(inb && inc);
        any_in   |= (int)inb;
        float dx = lx - cx, dy = ly - cy;
        float dist = dx * dx + dy * dy;
        if (dist < ball_v) { ball_v = dist; ball_i = l; }   // strict < keeps first occurrence
        float din = inb ? dist : INFINITY;
        if (din < bin_v) { bin_v = din; bin_i = l; }
    }

    __shared__ float s_v1[512]; __shared__ int s_i1[512];
    __shared__ float s_v2[512]; __shared__ int s_i2[512];
    __shared__ int s_c[512]; __shared__ int s_n[512];
    s_v1[tid] = bin_v;  s_i1[tid] = bin_i;
    s_v2[tid] = ball_v; s_i2[tid] = ball_i;
    s_c[tid] = any_cand; s_n[tid] = any_in;
    __syncthreads();
    for (int s = blockDim.x / 2; s > 0; s >>= 1) {
        if (tid < s) {
            if (s_v1[tid + s] < s_v1[tid] ||
                (s_v1[tid + s] == s_v1[tid] && s_i1[tid + s] < s_i1[tid])) {
                s_v1[tid] = s_v1[tid + s]; s_i1[tid] = s_i1[tid + s];
            }
            if (s_v2[tid + s] < s_v2[tid] ||
                (s_v2[tid + s] == s_v2[tid] && s_i2[tid + s] < s_i2[tid])) {
                s_v2[tid] = s_v2[tid + s]; s_i2[tid] = s_i2[tid + s];
            }
            s_c[tid] |= s_c[tid + s];
            s_n[tid] |= s_n[tid + s];
        }
        __syncthreads();
    }
    if (tid == 0) {
        int best = s_n[0] ? s_i1[0] : s_i2[0];
        flags[bm * 2]     = s_c[0];
        flags[bm * 2 + 1] = best;
        float* oi = info + (size_t)bm * 8;
        oi[0] = x1; oi[1] = y1; oi[2] = x2; oi[3] = y2;
        oi[4] = cx; oi[5] = cy; oi[6] = area; oi[7] = 0.0f;
    }
}

// Kernel 2 (fused): block = 256 consecutive locations of one batch image.
// Phase 1: per-location assignment + obj focal + box/GIoU/ctr losses, label
// parked in LDS. Phase 2: class focal streaming this block's 256xC logit
// rows as a flat coalesced float4 range (labels gathered from LDS).
// Per-block partials stored to private slots (no atomics).
__global__ void fused_loss_kernel(const float* __restrict__ boxes_xyxy,
                                  const float* __restrict__ box_deltas,
                                  const float* __restrict__ class_logits,
                                  const float* __restrict__ objectness,
                                  const float* __restrict__ centerness,
                                  const float* __restrict__ locations,
                                  const int* __restrict__ gt_labels,
                                  const int* __restrict__ gh_p,
                                  const int* __restrict__ gw_p,
                                  int L, int M, int C, int bpb, int nblk,
                                  const float* __restrict__ info,
                                  const int* __restrict__ flags,
                                  float* __restrict__ partials) {
    __shared__ float s_x1[MAXM], s_y1[MAXM], s_x2[MAXM], s_y2[MAXM];
    __shared__ float s_cx[MAXM], s_cy[MAXM], s_area[MAXM];
    __shared__ int   s_lab[MAXM], s_hc[MAXM], s_best[MAXM];
    __shared__ int   s_loclab[BLK];          // assigned label per location (-1 = neg)

    int b    = blockIdx.x / bpb;
    int lblk = blockIdx.x % bpb;
    int tid  = threadIdx.x;

    if (tid < M && tid < MAXM) {
        int bm = b * M + tid;
        const float* oi = info + (size_t)bm * 8;
        s_x1[tid] = oi[0]; s_y1[tid] = oi[1]; s_x2[tid] = oi[2]; s_y2[tid] = oi[3];
        s_cx[tid] = oi[4]; s_cy[tid] = oi[5]; s_area[tid] = oi[6];
        s_lab[tid]  = gt_labels[bm];
        s_hc[tid]   = flags[bm * 2];
        s_best[tid] = flags[bm * 2 + 1];
    }
    __syncthreads();

    int l0 = lblk * BLK;
    int l  = l0 + tid;
    float a_obj = 0.f, a_w = 0.f, a_l1 = 0.f, a_giou = 0.f, a_ctr = 0.f;
    int mylab = -1;

    if (l < L) {
        size_t bl = (size_t)b * L + l;
        const float2* loc2 = (const float2*)locations;
        float2 p2 = loc2[l];
        float lx = p2.x, ly = p2.y;
        float rx = POS_RADIUS_C / (float)gw_p[0];
        float ry = POS_RADIUS_C / (float)gh_p[0];

        float minc = INFINITY;
        int   asg  = -1;
        for (int m = 0; m < M; ++m) {
            bool cand;
            if (s_hc[m]) {
                cand = (lx > s_x1[m]) && (ly > s_y1[m]) && (lx < s_x2[m]) && (ly < s_y2[m])
                    && (fabsf(lx - s_cx[m]) <= rx) && (fabsf(ly - s_cy[m]) <= ry);
            } else {
                cand = (l == s_best[m]);
            }
            if (cand && (s_area[m] < minc)) { minc = s_area[m]; asg = m; }  // first-min wins
        }
        bool  pos   = (asg >= 0);
        float pos_f = pos ? 1.0f : 0.0f;
        mylab = pos ? s_lab[asg] : -1;

        a_obj = focal_elem(objectness[bl], pos_f);

        if (pos) {
            float ax1 = s_x1[asg], ay1 = s_y1[asg], ax2 = s_x2[asg], ay2 = s_y2[asg];
            float ltl = fmaxf(lx - ax1, 1e-6f);
            float ltt = fmaxf(ly - ay1, 1e-6f);
            float ltr = fmaxf(ax2 - lx, 1e-6f);
            float ltb = fmaxf(ay2 - ly, 1e-6f);
            float hor = fminf(ltl, ltr) / fmaxf(fmaxf(ltl, ltr), 1e-6f);
            float ver = fminf(ltt, ltb) / fmaxf(fmaxf(ltt, ltb), 1e-6f);
            float ctr_t = sqrtf(fmaxf(hor * ver, 0.0f));
            float wgt = fmaxf(ctr_t, 0.1f);
            a_w = wgt;

            // smooth-L1 (beta = 0.1), mean over 4 coords
            const float4 bd = *(const float4*)(box_deltas + bl * 4);
            float d0 = fabsf(bd.x - ltl), d1 = fabsf(bd.y - ltt);
            float d2 = fabsf(bd.z - ltr), d3 = fabsf(bd.w - ltb);
            float l1s = ((d0 < 0.1f) ? (0.5f * d0 * d0 / 0.1f) : (d0 - 0.05f))
                      + ((d1 < 0.1f) ? (0.5f * d1 * d1 / 0.1f) : (d1 - 0.05f))
                      + ((d2 < 0.1f) ? (0.5f * d2 * d2 / 0.1f) : (d2 - 0.05f))
                      + ((d3 < 0.1f) ? (0.5f * d3 * d3 / 0.1f) : (d3 - 0.05f));
            a_l1 = (l1s * 0.25f) * wgt;

            // GIoU
            const float4 pb = *(const float4*)(boxes_xyxy + bl * 4);
            float px1 = pb.x, py1 = pb.y, px2 = pb.z, py2 = pb.w;
            float ilx = fmaxf(px1, ax1), ily = fmaxf(py1, ay1);
            float irx = fminf(px2, ax2), iry = fminf(py2, ay2);
            float iw = fmaxf(irx - ilx, 0.f), ih = fmaxf(iry - ily, 0.f);
            float inter = iw * ih;
            float ap = fmaxf(px2 - px1, 0.f) * fmaxf(py2 - py1, 0.f);
            float ag = fmaxf(ax2 - ax1, 0.f) * fmaxf(ay2 - ay1, 0.f);
            float un = ap + ag - inter;
            float iou = inter / fmaxf(un, 1e-6f);
            float hlx = fminf(px1, ax1), hly = fminf(py1, ay1);
            float hrx = fmaxf(px2, ax2), hry = fmaxf(py2, ay2);
            float hw = fmaxf(hrx - hlx, 0.f), hh = fmaxf(hry - hly, 0.f);
            float hull = hw * hh;
            float giou = iou - (hull - un) / fmaxf(hull, 1e-6f);
            a_giou = (1.0f - giou) * wgt;

            // centerness BCE
            float xc = centerness[bl];
            float bce = fmaxf(xc, 0.f) - xc * ctr_t + __logf(1.0f + __expf(-fabsf(xc)));
            a_ctr = bce * wgt;
        }
    }
    s_loclab[tid] = mylab;
    __syncthreads();

    // Phase 2: class focal over this block's rows [l0, l0+nrows) x C.
    float a_cls = 0.f;
    int nrows = L - l0; if (nrows > BLK) nrows = BLK;
    int C4 = C >> 2;
    if (C4 > 0) {
        const float4* cl4 = (const float4*)(class_logits + ((size_t)b * L + l0) * C);
        int total_l = nrows * C4;
        int q  = tid / C4;                 // local row of this element
        int r  = tid - q * C4;             // float4 index within row
        int dq = BLK / C4, dr = BLK - dq * C4;
        for (int it = tid; it < total_l; it += BLK) {
            int lv = s_loclab[q];
            float4 v = cl4[it];
            int c0 = r << 2;
            a_cls += focal_elem(v.x, (c0     == lv) ? 1.f : 0.f);
            a_cls += focal_elem(v.y, (c0 + 1 == lv) ? 1.f : 0.f);
            a_cls += focal_elem(v.z, (c0 + 2 == lv) ? 1.f : 0.f);
            a_cls += focal_elem(v.w, (c0 + 3 == lv) ? 1.f : 0.f);
            q += dq; r += dr;
            if (r >= C4) { ++q; r -= C4; }
        }
    }
    int crem = C - (C4 << 2);              // leftover classes (C % 4) — rare path
    if (crem && l < L) {
        const float* rowp = class_logits + ((size_t)b * L + l) * C + (C4 << 2);
        for (int j = 0; j < crem; ++j)
            a_cls += focal_elem(rowp[j], ((C4 << 2) + j == mylab) ? 1.f : 0.f);
    }

    // wave shuffle reduce, LDS across waves, thread 0 stores 6 partials
    for (int off = 32; off > 0; off >>= 1) {
        a_obj  += __shfl_down(a_obj,  off);
        a_w    += __shfl_down(a_w,    off);
        a_l1   += __shfl_down(a_l1,   off);
        a_giou += __shfl_down(a_giou, off);
        a_ctr  += __shfl_down(a_ctr,  off);
        a_cls  += __shfl_down(a_cls,  off);
    }
    __shared__ float red[BLK / 64][6];
    int wid = tid >> 6;
    if ((tid & 63) == 0) {
        red[wid][0] = a_obj; red[wid][1] = a_w; red[wid][2] = a_l1;
        red[wid][3] = a_giou; red[wid][4] = a_ctr; red[wid][5] = a_cls;
    }
    __syncthreads();
    if (tid == 0) {
        float r0 = 0.f, r1 = 0.f, r2 = 0.f, r3 = 0.f, r4 = 0.f, r5 = 0.f;
        for (int w2 = 0; w2 < BLK / 64; ++w2) {
            r0 += red[w2][0]; r1 += red[w2][1]; r2 += red[w2][2];
            r3 += red[w2][3]; r4 += red[w2][4]; r5 += red[w2][5];
        }
        int blk = (int)blockIdx.x;
        partials[0 * nblk + blk] = r0;   // obj
        partials[1 * nblk + blk] = r1;   // wsum
        partials[2 * nblk + blk] = r2;   // l1
        partials[3 * nblk + blk] = r3;   // giou
        partials[4 * nblk + blk] = r4;   // ctr
        partials[5 * nblk + blk] = r5;   // cls
    }
}

// Kernel 3: single-block deterministic reduction over all partials + combine.
__global__ void finalize_kernel(const float* __restrict__ partials, int nblk,
                                float* __restrict__ out,
                                float invBL, float invBLC) {
    int tid = threadIdx.x;
    float r[6] = {0.f, 0.f, 0.f, 0.f, 0.f, 0.f};
    for (int i = tid; i < nblk; i += blockDim.x) {
        r[0] += partials[0 * nblk + i];
        r[1] += partials[1 * nblk + i];
        r[2] += partials[2 * nblk + i];
        r[3] += partials[3 * nblk + i];
        r[4] += partials[4 * nblk + i];
        r[5] += partials[5 * nblk + i];
    }
    __shared__ float red[256][6];
    for (int j = 0; j < 6; ++j) red[tid][j] = r[j];
    __syncthreads();
    for (int s = (int)blockDim.x / 2; s > 0; s >>= 1) {
        if (tid < s) {
            for (int j = 0; j < 6; ++j) red[tid][j] += red[tid + s][j];
        }
        __syncthreads();
    }
    if (tid == 0) {
        float obj  = red[0][0] * invBL;
        float wsum = red[0][1];
        float l1   = red[0][2] / wsum;
        float giou = red[0][3] / wsum;
        float ctr  = red[0][4] / wsum;
        float cls  = red[0][5] * invBLC;
        out[0] = OBJ_W_C * obj + CTR_W_C * ctr + CLS_W_C * cls + BOX_W_C * l1 + GIOU_W_C * giou;
    }
}

extern "C" void kernel_launch(void* const* d_in, const int* in_sizes, int n_in,
                              void* d_out, int out_size, void* d_ws, size_t ws_size,
                              hipStream_t stream) {
    const float* boxes_xyxy   = (const float*)d_in[0];
    const float* box_deltas   = (const float*)d_in[1];
    const float* class_logits = (const float*)d_in[2];
    const float* objectness   = (const float*)d_in[3];
    const float* centerness   = (const float*)d_in[4];
    const float* locations    = (const float*)d_in[5];
    const float* gt_boxes     = (const float*)d_in[6];
    const int*   gt_labels    = (const int*)d_in[7];
    const int*   gh           = (const int*)d_in[8];
    const int*   gw           = (const int*)d_in[9];

    int L = in_sizes[5] / 2;             // locations: (L,2)
    int B = in_sizes[3] / L;             // objectness: (B,L)
    int C = in_sizes[2] / in_sizes[3];   // class_logits: (B,L,C)
    int M = in_sizes[7] / B;             // gt_labels: (B,M)

    int bpb  = (L + BLK - 1) / BLK;
    int nblk = B * bpb;

    // ws layout (all 64B-aligned):
    //   flags    : B*M*2 int
    //   info     : B*M*8 float
    //   partials : 6*nblk float (per-block sums, SoA)
    char* p = (char*)d_ws;
    int*   flags  = (int*)p;              p += ((size_t)B * M * 2 * sizeof(int) + 63) / 64 * 64;
    float* info   = (float*)p;            p += ((size_t)B * M * 8 * sizeof(float) + 63) / 64 * 64;
    float* partials = (float*)p;

    gt_assign_kernel<<<B * M, 512, 0, stream>>>(locations, gt_boxes, gh, gw,
                                                L, M, info, flags);

    fused_loss_kernel<<<nblk, BLK, 0, stream>>>(boxes_xyxy, box_deltas,
                                                class_logits, objectness,
                                                centerness, locations,
                                                gt_labels, gh, gw,
                                                L, M, C, bpb, nblk,
                                                info, flags, partials);

    float invBL  = (float)(1.0 / ((double)B * (double)L));
    float invBLC = (float)(1.0 / ((double)B * (double)L * (double)C));
    finalize_kernel<<<1, 256, 0, stream>>>(partials, nblk, (float*)d_out,
                                           invBL, invBLC);
}

// Round 5
// 176.861 us; speedup vs baseline: 2.9039x; 1.0159x over previous
//
#include <hip/hip_runtime.h>
#include <cstdint>
#include <cstddef>
#include <math.h>

#define BOX_W_C  5.0f
#define GIOU_W_C 2.0f
#define OBJ_W_C  1.0f
#define CLS_W_C  1.5f
#define CTR_W_C  0.5f
#define POS_RADIUS_C 1.0f
#define MAXM 128
#define BLK 256

// full focal element: a_t * ce * (1-p_t)^2, alpha=0.25, gamma=2, t in {0,1}
__device__ __forceinline__ float focal_elem(float x, float t) {
    float ax = fabsf(x);
    float e  = __expf(-ax);
    float lg = __logf(1.0f + e);              // log1p(exp(-|x|))
    float ce = fmaxf(x, 0.0f) - x * t + lg;
    float inv = 1.0f / (1.0f + e);
    float p  = (x >= 0.0f) ? inv : e * inv;   // sigmoid
    float p_t = p * t + (1.0f - p) * (1.0f - t);
    float a_t = 0.25f * t + 0.75f * (1.0f - t);
    float om  = 1.0f - p_t;
    return a_t * ce * om * om;
}

// negative-target focal (t = 0): 0.75 * (max(x,0)+log1p(e^-|x|)) * sigmoid(x)^2
__device__ __forceinline__ float focal_neg(float x) {
    float ax = fabsf(x);
    float e  = __expf(-ax);
    float lg = __logf(1.0f + e);
    float ce = fmaxf(x, 0.0f) + lg;
    float inv = 1.0f / (1.0f + e);
    float p  = (x >= 0.0f) ? inv : e * inv;
    return 0.75f * ce * p * p;
}

// focal(x, t=1) - focal(x, t=0), shared transcendentals
__device__ __forceinline__ float focal_pos_correction(float x) {
    float ax = fabsf(x);
    float e  = __expf(-ax);
    float lg = __logf(1.0f + e);
    float relu = fmaxf(x, 0.0f);
    float inv = 1.0f / (1.0f + e);
    float p  = (x >= 0.0f) ? inv : e * inv;
    float om = 1.0f - p;
    float f1 = 0.25f * (relu - x + lg) * om * om;
    float f0 = 0.75f * (relu + lg) * p * p;
    return f1 - f0;
}

// Kernel 1: one block per (b,m). Per-GT: box coords, area, has_candidate,
// fallback best location (first-occurrence argmin, jnp.argmin semantics).
__global__ void gt_assign_kernel(const float* __restrict__ locations,
                                 const float* __restrict__ gt_boxes,
                                 const int* __restrict__ gh_p,
                                 const int* __restrict__ gw_p,
                                 int L, int M,
                                 float* __restrict__ info,
                                 int* __restrict__ flags) {
    int bm  = blockIdx.x;
    int tid = threadIdx.x;

    const float* gb = gt_boxes + (size_t)bm * 4;
    float cx = gb[0], cy = gb[1], w = gb[2], h = gb[3];
    float x1 = cx - w * 0.5f, y1 = cy - h * 0.5f;
    float x2 = cx + w * 0.5f, y2 = cy + h * 0.5f;
    float area = w * h;
    float rx = POS_RADIUS_C / (float)gw_p[0];
    float ry = POS_RADIUS_C / (float)gh_p[0];

    float bin_v  = INFINITY; int bin_i  = 0x7fffffff;  // argmin dist | inside_box
    float ball_v = INFINITY; int ball_i = 0x7fffffff;  // argmin dist (unmasked)
    int any_cand = 0, any_in = 0;

    const float2* loc2 = (const float2*)locations;
    for (int l = tid; l < L; l += blockDim.x) {
        float2 p2 = loc2[l];
        float lx = p2.x, ly = p2.y;
        bool inb = (lx > x1) && (ly > y1) && (lx < x2) && (ly < y2);
        bool inc = (fabsf(lx - cx) <= rx) && (fabsf(ly - cy) <= ry);
        any_cand |= (int)(inb && inc);
        any_in   |= (int)inb;
        float dx = lx - cx, dy = ly - cy;
        float dist = dx * dx + dy * dy;
        if (dist < ball_v) { ball_v = dist; ball_i = l; }   // strict < keeps first occurrence
        float din = inb ? dist : INFINITY;
        if (din < bin_v) { bin_v = din; bin_i = l; }
    }

    __shared__ float s_v1[512]; __shared__ int s_i1[512];
    __shared__ float s_v2[512]; __shared__ int s_i2[512];
    __shared__ int s_c[512]; __shared__ int s_n[512];
    s_v1[tid] = bin_v;  s_i1[tid] = bin_i;
    s_v2[tid] = ball_v; s_i2[tid] = ball_i;
    s_c[tid] = any_cand; s_n[tid] = any_in;
    __syncthreads();
    for (int s = blockDim.x / 2; s > 0; s >>= 1) {
        if (tid < s) {
            if (s_v1[tid + s] < s_v1[tid] ||
                (s_v1[tid + s] == s_v1[tid] && s_i1[tid + s] < s_i1[tid])) {
                s_v1[tid] = s_v1[tid + s]; s_i1[tid] = s_i1[tid + s];
            }
            if (s_v2[tid + s] < s_v2[tid] ||
                (s_v2[tid + s] == s_v2[tid] && s_i2[tid + s] < s_i2[tid])) {
                s_v2[tid] = s_v2[tid + s]; s_i2[tid] = s_i2[tid + s];
            }
            s_c[tid] |= s_c[tid + s];
            s_n[tid] |= s_n[tid + s];
        }
        __syncthreads();
    }
    if (tid == 0) {
        int best = s_n[0] ? s_i1[0] : s_i2[0];
        flags[bm * 2]     = s_c[0];
        flags[bm * 2 + 1] = best;
        float* oi = info + (size_t)bm * 8;
        oi[0] = x1; oi[1] = y1; oi[2] = x2; oi[3] = y2;
        oi[4] = cx; oi[5] = cy; oi[6] = area; oi[7] = 0.0f;
    }
}

// Kernel 2 (fused): block = 256 consecutive locations of one batch image.
// Phase 1: per-location assignment + obj focal + box/GIoU/ctr losses.
// Phase 2: class focal = flat streaming sum of focal_neg over the block's
// contiguous 256*C logits (no LDS, no index tracking), plus a per-thread
// correction f1(x_lab)-f0(x_lab) for positive locations (~2% of threads).
// Per-block partials stored to private slots (no atomics).
__global__ void fused_loss_kernel(const float* __restrict__ boxes_xyxy,
                                  const float* __restrict__ box_deltas,
                                  const float* __restrict__ class_logits,
                                  const float* __restrict__ objectness,
                                  const float* __restrict__ centerness,
                                  const float* __restrict__ locations,
                                  const int* __restrict__ gt_labels,
                                  const int* __restrict__ gh_p,
                                  const int* __restrict__ gw_p,
                                  int L, int M, int C, int bpb, int nblk,
                                  const float* __restrict__ info,
                                  const int* __restrict__ flags,
                                  float* __restrict__ partials) {
    __shared__ float s_x1[MAXM], s_y1[MAXM], s_x2[MAXM], s_y2[MAXM];
    __shared__ float s_cx[MAXM], s_cy[MAXM], s_area[MAXM];
    __shared__ int   s_lab[MAXM], s_hc[MAXM], s_best[MAXM];

    int b    = blockIdx.x / bpb;
    int lblk = blockIdx.x % bpb;
    int tid  = threadIdx.x;

    if (tid < M && tid < MAXM) {
        int bm = b * M + tid;
        const float* oi = info + (size_t)bm * 8;
        s_x1[tid] = oi[0]; s_y1[tid] = oi[1]; s_x2[tid] = oi[2]; s_y2[tid] = oi[3];
        s_cx[tid] = oi[4]; s_cy[tid] = oi[5]; s_area[tid] = oi[6];
        s_lab[tid]  = gt_labels[bm];
        s_hc[tid]   = flags[bm * 2];
        s_best[tid] = flags[bm * 2 + 1];
    }
    __syncthreads();

    int l0 = lblk * BLK;
    int l  = l0 + tid;
    float a_obj = 0.f, a_w = 0.f, a_l1 = 0.f, a_giou = 0.f, a_ctr = 0.f;
    float a_cls = 0.f;
    int mylab = -1;

    if (l < L) {
        size_t bl = (size_t)b * L + l;
        const float2* loc2 = (const float2*)locations;
        float2 p2 = loc2[l];
        float lx = p2.x, ly = p2.y;
        float rx = POS_RADIUS_C / (float)gw_p[0];
        float ry = POS_RADIUS_C / (float)gh_p[0];

        float minc = INFINITY;
        int   asg  = -1;
        for (int m = 0; m < M; ++m) {
            bool cand;
            if (s_hc[m]) {
                cand = (lx > s_x1[m]) && (ly > s_y1[m]) && (lx < s_x2[m]) && (ly < s_y2[m])
                    && (fabsf(lx - s_cx[m]) <= rx) && (fabsf(ly - s_cy[m]) <= ry);
            } else {
                cand = (l == s_best[m]);
            }
            if (cand && (s_area[m] < minc)) { minc = s_area[m]; asg = m; }  // first-min wins
        }
        bool  pos   = (asg >= 0);
        float pos_f = pos ? 1.0f : 0.0f;
        mylab = pos ? s_lab[asg] : -1;

        a_obj = focal_elem(objectness[bl], pos_f);

        if (pos) {
            float ax1 = s_x1[asg], ay1 = s_y1[asg], ax2 = s_x2[asg], ay2 = s_y2[asg];
            float ltl = fmaxf(lx - ax1, 1e-6f);
            float ltt = fmaxf(ly - ay1, 1e-6f);
            float ltr = fmaxf(ax2 - lx, 1e-6f);
            float ltb = fmaxf(ay2 - ly, 1e-6f);
            float hor = fminf(ltl, ltr) / fmaxf(fmaxf(ltl, ltr), 1e-6f);
            float ver = fminf(ltt, ltb) / fmaxf(fmaxf(ltt, ltb), 1e-6f);
            float ctr_t = sqrtf(fmaxf(hor * ver, 0.0f));
            float wgt = fmaxf(ctr_t, 0.1f);
            a_w = wgt;

            // smooth-L1 (beta = 0.1), mean over 4 coords
            const float4 bd = *(const float4*)(box_deltas + bl * 4);
            float d0 = fabsf(bd.x - ltl), d1 = fabsf(bd.y - ltt);
            float d2 = fabsf(bd.z - ltr), d3 = fabsf(bd.w - ltb);
            float l1s = ((d0 < 0.1f) ? (0.5f * d0 * d0 / 0.1f) : (d0 - 0.05f))
                      + ((d1 < 0.1f) ? (0.5f * d1 * d1 / 0.1f) : (d1 - 0.05f))
                      + ((d2 < 0.1f) ? (0.5f * d2 * d2 / 0.1f) : (d2 - 0.05f))
                      + ((d3 < 0.1f) ? (0.5f * d3 * d3 / 0.1f) : (d3 - 0.05f));
            a_l1 = (l1s * 0.25f) * wgt;

            // GIoU
            const float4 pb = *(const float4*)(boxes_xyxy + bl * 4);
            float px1 = pb.x, py1 = pb.y, px2 = pb.z, py2 = pb.w;
            float ilx = fmaxf(px1, ax1), ily = fmaxf(py1, ay1);
            float irx = fminf(px2, ax2), iry = fminf(py2, ay2);
            float iw = fmaxf(irx - ilx, 0.f), ih = fmaxf(iry - ily, 0.f);
            float inter = iw * ih;
            float ap = fmaxf(px2 - px1, 0.f) * fmaxf(py2 - py1, 0.f);
            float ag = fmaxf(ax2 - ax1, 0.f) * fmaxf(ay2 - ay1, 0.f);
            float un = ap + ag - inter;
            float iou = inter / fmaxf(un, 1e-6f);
            float hlx = fminf(px1, ax1), hly = fminf(py1, ay1);
            float hrx = fmaxf(px2, ax2), hry = fmaxf(py2, ay2);
            float hw = fmaxf(hrx - hlx, 0.f), hh = fmaxf(hry - hly, 0.f);
            float hull = hw * hh;
            float giou = iou - (hull - un) / fmaxf(hull, 1e-6f);
            a_giou = (1.0f - giou) * wgt;

            // centerness BCE
            float xc = centerness[bl];
            float bce = fmaxf(xc, 0.f) - xc * ctr_t + __logf(1.0f + __expf(-fabsf(xc)));
            a_ctr = bce * wgt;
        }

        // positive-class correction for this thread's own row (rare path)
        if (mylab >= 0) {
            float xl = class_logits[bl * (size_t)C + mylab];
            a_cls += focal_pos_correction(xl);
        }
    }

    // Phase 2: flat streaming focal_neg over rows [l0, l0+nrows) x C.
    {
        int nrows = L - l0; if (nrows > BLK) nrows = BLK;
        int C4 = C >> 2;
        if (C4 > 0) {
            const float4* cl4 = (const float4*)(class_logits + ((size_t)b * L + l0) * C);
            int total4 = nrows * C4;
            for (int it = tid; it < total4; it += BLK) {
                float4 v = cl4[it];
                a_cls += focal_neg(v.x);
                a_cls += focal_neg(v.y);
                a_cls += focal_neg(v.z);
                a_cls += focal_neg(v.w);
            }
        }
        int crem = C - (C4 << 2);              // leftover classes (C % 4) — rare path
        if (crem) {
            const float* base = class_logits + ((size_t)b * L + l0) * C + (C4 << 2);
            for (int rr = tid; rr < nrows; rr += BLK)
                for (int j = 0; j < crem; ++j)
                    a_cls += focal_neg(base[(size_t)rr * C + j]);
            // note: tail elements of a positive row with c == mylab are impossible
            // here only if mylab < C4*4; general correctness: correction already
            // handled mylab generically above (focal_pos_correction applied to the
            // exact element regardless of its position), and focal_neg is applied
            // to every element exactly once, so the tail path is consistent.
        }
    }

    // wave shuffle reduce, LDS across waves, thread 0 stores 6 partials
    for (int off = 32; off > 0; off >>= 1) {
        a_obj  += __shfl_down(a_obj,  off);
        a_w    += __shfl_down(a_w,    off);
        a_l1   += __shfl_down(a_l1,   off);
        a_giou += __shfl_down(a_giou, off);
        a_ctr  += __shfl_down(a_ctr,  off);
        a_cls  += __shfl_down(a_cls,  off);
    }
    __shared__ float red[BLK / 64][6];
    int wid = tid >> 6;
    if ((tid & 63) == 0) {
        red[wid][0] = a_obj; red[wid][1] = a_w; red[wid][2] = a_l1;
        red[wid][3] = a_giou; red[wid][4] = a_ctr; red[wid][5] = a_cls;
    }
    __syncthreads();
    if (tid == 0) {
        float r0 = 0.f, r1 = 0.f, r2 = 0.f, r3 = 0.f, r4 = 0.f, r5 = 0.f;
        for (int w2 = 0; w2 < BLK / 64; ++w2) {
            r0 += red[w2][0]; r1 += red[w2][1]; r2 += red[w2][2];
            r3 += red[w2][3]; r4 += red[w2][4]; r5 += red[w2][5];
        }
        int blk = (int)blockIdx.x;
        partials[0 * nblk + blk] = r0;   // obj
        partials[1 * nblk + blk] = r1;   // wsum
        partials[2 * nblk + blk] = r2;   // l1
        partials[3 * nblk + blk] = r3;   // giou
        partials[4 * nblk + blk] = r4;   // ctr
        partials[5 * nblk + blk] = r5;   // cls
    }
}

// Kernel 3: single-block deterministic reduction over all partials + combine.
__global__ void finalize_kernel(const float* __restrict__ partials, int nblk,
                                float* __restrict__ out,
                                float invBL, float invBLC) {
    int tid = threadIdx.x;
    float r[6] = {0.f, 0.f, 0.f, 0.f, 0.f, 0.f};
    for (int i = tid; i < nblk; i += blockDim.x) {
        r[0] += partials[0 * nblk + i];
        r[1] += partials[1 * nblk + i];
        r[2] += partials[2 * nblk + i];
        r[3] += partials[3 * nblk + i];
        r[4] += partials[4 * nblk + i];
        r[5] += partials[5 * nblk + i];
    }
    __shared__ float red[256][6];
    for (int j = 0; j < 6; ++j) red[tid][j] = r[j];
    __syncthreads();
    for (int s = (int)blockDim.x / 2; s > 0; s >>= 1) {
        if (tid < s) {
            for (int j = 0; j < 6; ++j) red[tid][j] += red[tid + s][j];
        }
        __syncthreads();
    }
    if (tid == 0) {
        float obj  = red[0][0] * invBL;
        float wsum = red[0][1];
        float l1   = red[0][2] / wsum;
        float giou = red[0][3] / wsum;
        float ctr  = red[0][4] / wsum;
        float cls  = red[0][5] * invBLC;
        out[0] = OBJ_W_C * obj + CTR_W_C * ctr + CLS_W_C * cls + BOX_W_C * l1 + GIOU_W_C * giou;
    }
}

extern "C" void kernel_launch(void* const* d_in, const int* in_sizes, int n_in,
                              void* d_out, int out_size, void* d_ws, size_t ws_size,
                              hipStream_t stream) {
    const float* boxes_xyxy   = (const float*)d_in[0];
    const float* box_deltas   = (const float*)d_in[1];
    const float* class_logits = (const float*)d_in[2];
    const float* objectness   = (const float*)d_in[3];
    const float* centerness   = (const float*)d_in[4];
    const float* locations    = (const float*)d_in[5];
    const float* gt_boxes     = (const float*)d_in[6];
    const int*   gt_labels    = (const int*)d_in[7];
    const int*   gh           = (const int*)d_in[8];
    const int*   gw           = (const int*)d_in[9];

    int L = in_sizes[5] / 2;             // locations: (L,2)
    int B = in_sizes[3] / L;             // objectness: (B,L)
    int C = in_sizes[2] / in_sizes[3];   // class_logits: (B,L,C)
    int M = in_sizes[7] / B;             // gt_labels: (B,M)

    int bpb  = (L + BLK - 1) / BLK;
    int nblk = B * bpb;

    // ws layout (all 64B-aligned):
    //   flags    : B*M*2 int
    //   info     : B*M*8 float
    //   partials : 6*nblk float (per-block sums, SoA)
    char* p = (char*)d_ws;
    int*   flags  = (int*)p;              p += ((size_t)B * M * 2 * sizeof(int) + 63) / 64 * 64;
    float* info   = (float*)p;            p += ((size_t)B * M * 8 * sizeof(float) + 63) / 64 * 64;
    float* partials = (float*)p;

    gt_assign_kernel<<<B * M, 512, 0, stream>>>(locations, gt_boxes, gh, gw,
                                                L, M, info, flags);

    fused_loss_kernel<<<nblk, BLK, 0, stream>>>(boxes_xyxy, box_deltas,
                                                class_logits, objectness,
                                                centerness, locations,
                                                gt_labels, gh, gw,
                                                L, M, C, bpb, nblk,
                                                info, flags, partials);

    float invBL  = (float)(1.0 / ((double)B * (double)L));
    float invBLC = (float)(1.0 / ((double)B * (double)L * (double)C));
    finalize_kernel<<<1, 256, 0, stream>>>(partials, nblk, (float*)d_out,
                                           invBL, invBLC);
}